// Round 1
// baseline (2212.067 us; speedup 1.0000x reference)
//
#include <hip/hip_runtime.h>

#define NPILLARS 96000
#define MPTS 32
#define NCHAN 64
#define NXC 432
#define NYC 496
#define NB 8
#define NCELLS (NXC*NYC)          // 214272
#define PXc 0.16f
#define PYc 0.16f
#define PZc 4.0f
#define XOFF (0.08f)              // PX/2 + X0
#define YOFF (0.08f - 39.68f)     // PY/2 + Y0
#define ZOFF (2.0f - 3.0f)        // PZ/2 + Z0
#define BN_EPS 1e-3f

typedef __attribute__((ext_vector_type(8))) short short8;
typedef __attribute__((ext_vector_type(16))) float float16;

__device__ __forceinline__ short f2bf(float x) {
    union { float f; unsigned u; } v; v.f = x;
    unsigned r = v.u + 0x7FFFu + ((v.u >> 16) & 1u);  // RNE
    return (short)(r >> 16);
}

// Pass 1: 65-value moment reduction of feats + per-cell winner (last-write-wins => max p).
// One wave handles 2 pillars per iter: lanes 0-31 -> p0 (m=lane), lanes 32-63 -> p1.
__global__ void k_moments(const float4* __restrict__ pillars,
                          const int* __restrict__ coords,
                          const int* __restrict__ num_points,
                          float* __restrict__ mom, int* __restrict__ winner) {
    const int tid  = threadIdx.x;
    const int lane = tid & 63;
    const int sub  = lane & 31;
    const int half = lane >> 5;
    const int wid    = (blockIdx.x * blockDim.x + tid) >> 6;
    const int nwaves = (gridDim.x * blockDim.x) >> 6;

    float s[10];
    float q[55];
#pragma unroll
    for (int i = 0; i < 10; i++) s[i] = 0.f;
#pragma unroll
    for (int i = 0; i < 55; i++) q[i] = 0.f;

    for (int base = wid * 2; base < NPILLARS; base += nwaves * 2) {
        const int p = base + half;   // NPILLARS even -> always valid, no divergence
        float4 pt = pillars[p * MPTS + sub];
        float sx = pt.x, sy = pt.y, sz = pt.z;
#pragma unroll
        for (int m = 16; m >= 1; m >>= 1) {   // masks <32: stays within each half
            sx += __shfl_xor(sx, m);
            sy += __shfl_xor(sy, m);
            sz += __shfl_xor(sz, m);
        }
        const float n = (float)num_points[p];
        const float mx = sx / n, my = sy / n, mz = sz / n;
        const int   cb  = coords[p*4+0];
        const int   czi = coords[p*4+1], cyi = coords[p*4+2], cxi = coords[p*4+3];
        const float ctx = (float)cxi * PXc + XOFF;
        const float cty = (float)cyi * PYc + YOFF;
        const float ctz = (float)czi * PZc + ZOFF;
        float f[10];
        f[0]=pt.x; f[1]=pt.y; f[2]=pt.z; f[3]=pt.w;
        f[4]=pt.x-mx;  f[5]=pt.y-my;  f[6]=pt.z-mz;
        f[7]=pt.x-ctx; f[8]=pt.y-cty; f[9]=pt.z-ctz;
#pragma unroll
        for (int i = 0; i < 10; i++) s[i] += f[i];
        int idx = 0;
#pragma unroll
        for (int i = 0; i < 10; i++)
#pragma unroll
            for (int j = i; j < 10; j++) { q[idx] = fmaf(f[i], f[j], q[idx]); idx++; }
        if (sub == 0) {
            const int cell = czi + cyi * NXC + cxi;
            atomicMax(&winner[cb * NCELLS + cell], p);
        }
    }
#pragma unroll
    for (int i = 0; i < 10; i++) {
        float v = s[i];
        for (int m = 32; m >= 1; m >>= 1) v += __shfl_xor(v, m);
        if (lane == 0) atomicAdd(&mom[i], v);
    }
#pragma unroll
    for (int i = 0; i < 55; i++) {
        float v = q[i];
        for (int m = 32; m >= 1; m >>= 1) v += __shfl_xor(v, m);
        if (lane == 0) atomicAdd(&mom[10 + i], v);
    }
}

// Pass 1b: fold moments through W -> per-channel scale/shift (double precision, trivial cost).
__global__ void k_finalize(const float* __restrict__ mom,
                           const float* __restrict__ W,
                           const float* __restrict__ gamma,
                           const float* __restrict__ beta,
                           float* __restrict__ ss) {
    const int c = threadIdx.x;  // 0..63
    const double invN = 1.0 / ((double)NPILLARS * (double)MPTS);
    double wv[10];
#pragma unroll
    for (int i = 0; i < 10; i++) wv[i] = (double)W[i * NCHAN + c];
    double mu = 0.0;
#pragma unroll
    for (int i = 0; i < 10; i++) mu += (double)mom[i] * wv[i];
    mu *= invN;
    double e2 = 0.0;
    int idx = 0;
#pragma unroll
    for (int i = 0; i < 10; i++)
#pragma unroll
        for (int j = i; j < 10; j++) {
            double t = (double)mom[10 + idx] * wv[i] * wv[j];
            e2 += (i == j) ? t : 2.0 * t;
            idx++;
        }
    e2 *= invN;
    const double var = e2 - mu * mu;
    const float scale = (float)((double)gamma[c] / sqrt(var + (double)BN_EPS));
    const float shift = beta[c] - (float)mu * scale;
    ss[c] = scale;
    ss[64 + c] = shift;
}

// Pass 2: per-pillar (M=32 x K=10) @ (10 x 64) via 2x v_mfma_f32_32x32x16_bf16,
// fused BN+relu+max over M, compact coalesced pv write.
// A-frag: row m = lane&31, k = (lane>>5)*8 + r. B-frag: col n = lane&31, same k map.
// C: col = lane&31 (HW-verified); rows covered by 16 regs x 2 halves (we max all).
__global__ void k_pv(const float4* __restrict__ pillars,
                     const int* __restrict__ coords,
                     const int* __restrict__ num_points,
                     const float* __restrict__ W,
                     const float* __restrict__ ss,
                     float* __restrict__ pv) {
    const int tid  = threadIdx.x;
    const int lane = tid & 63;
    const int sub  = lane & 31;
    const int half = lane >> 5;
    const int wid    = (blockIdx.x * blockDim.x + tid) >> 6;
    const int nwaves = (gridDim.x * blockDim.x) >> 6;

    short8 bf0, bf1;
#pragma unroll
    for (int r = 0; r < 8; r++) {
        const int k = half * 8 + r;
        bf0[r] = (k < 10) ? f2bf(W[k * NCHAN + sub])      : (short)0;
        bf1[r] = (k < 10) ? f2bf(W[k * NCHAN + 32 + sub]) : (short)0;
    }
    const float scale0 = ss[sub],      shift0 = ss[64 + sub];
    const float scale1 = ss[32 + sub], shift1 = ss[96 + sub];

    for (int p = wid; p < NPILLARS; p += nwaves) {
        float4 pt = pillars[p * MPTS + sub];   // both halves load same m=sub (L1 hit)
        float sx = pt.x, sy = pt.y, sz = pt.z;
#pragma unroll
        for (int m = 16; m >= 1; m >>= 1) {
            sx += __shfl_xor(sx, m);
            sy += __shfl_xor(sy, m);
            sz += __shfl_xor(sz, m);
        }
        const float n = (float)num_points[p];
        const float mx = sx / n, my = sy / n, mz = sz / n;
        const float ctx = (float)coords[p*4+3] * PXc + XOFF;
        const float cty = (float)coords[p*4+2] * PYc + YOFF;
        const float ctz = (float)coords[p*4+1] * PZc + ZOFF;
        float f[10];
        f[0]=pt.x; f[1]=pt.y; f[2]=pt.z; f[3]=pt.w;
        f[4]=pt.x-mx;  f[5]=pt.y-my;  f[6]=pt.z-mz;
        f[7]=pt.x-ctx; f[8]=pt.y-cty; f[9]=pt.z-ctz;
        short8 a;
#pragma unroll
        for (int r = 0; r < 8; r++) {
            const int k = half * 8 + r;
            a[r] = (k < 10) ? f2bf(f[k]) : (short)0;
        }
        float16 acc0 = {};
        float16 acc1 = {};
        acc0 = __builtin_amdgcn_mfma_f32_32x32x16_bf16(a, bf0, acc0, 0, 0, 0);
        acc1 = __builtin_amdgcn_mfma_f32_32x32x16_bf16(a, bf1, acc1, 0, 0, 0);
        // relu-then-max == max(0, max_m(scale*h+shift)); init 0 gives the relu floor.
        float m0 = 0.f, m1 = 0.f;
#pragma unroll
        for (int r = 0; r < 16; r++) {
            m0 = fmaxf(m0, fmaf(acc0[r], scale0, shift0));
            m1 = fmaxf(m1, fmaf(acc1[r], scale1, shift1));
        }
        m0 = fmaxf(m0, __shfl_xor(m0, 32));  // combine the two row-halves
        m1 = fmaxf(m1, __shfl_xor(m1, 32));
        pv[p * NCHAN + lane] = half ? m1 : m0;  // lanes 0-31: cols 0-31, lanes 32-63: cols 32-63
    }
}

// Pass 3: output-ordered expand — every output element written coalesced exactly once.
// Merges the zero-fill with the scatter (no 438MB memset + RMW scatter).
__global__ void k_expand(const int* __restrict__ winner,
                         const float* __restrict__ pv,
                         float* __restrict__ out) {
    const int idx = blockIdx.x * blockDim.x + threadIdx.x;  // group of 4 cells
    const int total4 = NB * NCELLS / 4;
    if (idx >= total4) return;
    const int b    = (idx << 2) / NCELLS;   // NCELLS % 4 == 0: groups never straddle b
    const int cell = (idx << 2) - b * NCELLS;
    const int4 w = ((const int4*)winner)[idx];
    float* obase = out + (size_t)b * NCHAN * NCELLS + cell;
#pragma unroll 4
    for (int c = 0; c < NCHAN; c++) {
        float4 v;
        v.x = (w.x >= 0) ? pv[w.x * NCHAN + c] : 0.f;
        v.y = (w.y >= 0) ? pv[w.y * NCHAN + c] : 0.f;
        v.z = (w.z >= 0) ? pv[w.z * NCHAN + c] : 0.f;
        v.w = (w.w >= 0) ? pv[w.w * NCHAN + c] : 0.f;
        *reinterpret_cast<float4*>(obase + (size_t)c * NCELLS) = v;
    }
}

extern "C" void kernel_launch(void* const* d_in, const int* in_sizes, int n_in,
                              void* d_out, int out_size, void* d_ws, size_t ws_size,
                              hipStream_t stream) {
    const float4* pillars    = (const float4*)d_in[0];
    const int*    coords     = (const int*)d_in[1];
    const int*    num_points = (const int*)d_in[2];
    const float*  W          = (const float*)d_in[3];
    const float*  gamma      = (const float*)d_in[4];
    const float*  beta       = (const float*)d_in[5];
    float* out = (float*)d_out;

    char* ws = (char*)d_ws;
    float* mom    = (float*)ws;            // 65 floats
    float* ss     = (float*)(ws + 512);    // 128 floats (scale[64], shift[64])
    int*   winner = (int*)(ws + 4096);     // NB*NCELLS ints = 6.86 MB
    float* pv     = (float*)(ws + 4096 + (size_t)NB * NCELLS * sizeof(int)); // 24.6 MB

    hipMemsetAsync(mom, 0, 65 * sizeof(float), stream);
    hipMemsetAsync(winner, 0xFF, (size_t)NB * NCELLS * sizeof(int), stream);  // -1

    k_moments <<<1024, 256, 0, stream>>>(pillars, coords, num_points, mom, winner);
    k_finalize<<<1, 64, 0, stream>>>(mom, W, gamma, beta, ss);
    k_pv      <<<2048, 256, 0, stream>>>(pillars, coords, num_points, W, ss, pv);
    k_expand  <<<(NB * NCELLS / 4 + 255) / 256, 256, 0, stream>>>(winner, pv, out);
}

// Round 2
// 580.028 us; speedup vs baseline: 3.8137x; 3.8137x over previous
//
#include <hip/hip_runtime.h>

#define NPILLARS 96000
#define MPTS 32
#define NCHAN 64
#define NXC 432
#define NYC 496
#define NB 8
#define NCELLS (NXC*NYC)          // 214272
#define NBLK 1024                 // k_moments grid (must match launch)
#define PXc 0.16f
#define PYc 0.16f
#define PZc 4.0f
#define XOFF (0.08f)              // PX/2 + X0
#define YOFF (0.08f - 39.68f)     // PY/2 + Y0
#define ZOFF (2.0f - 3.0f)        // PZ/2 + Z0
#define BN_EPS 1e-3f

typedef __attribute__((ext_vector_type(8))) short short8;
typedef __attribute__((ext_vector_type(16))) float float16;

__device__ __forceinline__ short f2bf(float x) {
    union { float f; unsigned u; } v; v.f = x;
    unsigned r = v.u + 0x7FFFu + ((v.u >> 16) & 1u);  // RNE
    return (short)(r >> 16);
}

// Upper-triangle pair list: Q(flat_idx, i, j) for 0<=i<=j<10 (row-major).
#define PAIRS(Q) \
 Q(0,0,0) Q(1,0,1) Q(2,0,2) Q(3,0,3) Q(4,0,4) Q(5,0,5) Q(6,0,6) Q(7,0,7) Q(8,0,8) Q(9,0,9) \
 Q(10,1,1) Q(11,1,2) Q(12,1,3) Q(13,1,4) Q(14,1,5) Q(15,1,6) Q(16,1,7) Q(17,1,8) Q(18,1,9) \
 Q(19,2,2) Q(20,2,3) Q(21,2,4) Q(22,2,5) Q(23,2,6) Q(24,2,7) Q(25,2,8) Q(26,2,9) \
 Q(27,3,3) Q(28,3,4) Q(29,3,5) Q(30,3,6) Q(31,3,7) Q(32,3,8) Q(33,3,9) \
 Q(34,4,4) Q(35,4,5) Q(36,4,6) Q(37,4,7) Q(38,4,8) Q(39,4,9) \
 Q(40,5,5) Q(41,5,6) Q(42,5,7) Q(43,5,8) Q(44,5,9) \
 Q(45,6,6) Q(46,6,7) Q(47,6,8) Q(48,6,9) \
 Q(49,7,7) Q(50,7,8) Q(51,7,9) \
 Q(52,8,8) Q(53,8,9) \
 Q(54,9,9)

// Pass 1: 65-moment reduction of feats (named scalars -> VGPRs, no scratch)
// + per-cell winner (last-write-wins => max p). One wave = 2 pillars/iter.
__global__ __launch_bounds__(256, 4)
void k_moments(const float4* __restrict__ pillars,
               const int* __restrict__ coords,
               const int* __restrict__ num_points,
               float* __restrict__ partial,   // [65][NBLK], moment-major
               int* __restrict__ winner) {
    const int tid  = threadIdx.x;
    const int lane = tid & 63;
    const int sub  = lane & 31;
    const int half = lane >> 5;
    const int wv   = tid >> 6;                 // wave within block (0..3)
    const int wid    = (blockIdx.x * blockDim.x + tid) >> 6;
    const int nwaves = (gridDim.x * blockDim.x) >> 6;

    float s0=0.f,s1=0.f,s2=0.f,s3=0.f,s4=0.f,s5=0.f,s6=0.f,s7=0.f,s8=0.f,s9=0.f;
#define QDECL(idx,i,j) float q_##i##_##j = 0.f;
    PAIRS(QDECL)
#undef QDECL

    for (int base = wid * 2; base < NPILLARS; base += nwaves * 2) {
        const int p = base + half;   // NPILLARS even -> always valid
        float4 pt = pillars[p * MPTS + sub];
        float sx = pt.x, sy = pt.y, sz = pt.z;
#pragma unroll
        for (int m = 16; m >= 1; m >>= 1) {   // masks <32: stays within each half
            sx += __shfl_xor(sx, m);
            sy += __shfl_xor(sy, m);
            sz += __shfl_xor(sz, m);
        }
        const float n = (float)num_points[p];
        const float mx = sx / n, my = sy / n, mz = sz / n;
        const int   cb  = coords[p*4+0];
        const int   czi = coords[p*4+1], cyi = coords[p*4+2], cxi = coords[p*4+3];
        const float ctx = (float)cxi * PXc + XOFF;
        const float cty = (float)cyi * PYc + YOFF;
        const float ctz = (float)czi * PZc + ZOFF;
        const float f0=pt.x, f1=pt.y, f2=pt.z, f3=pt.w;
        const float f4=pt.x-mx,  f5=pt.y-my,  f6=pt.z-mz;
        const float f7=pt.x-ctx, f8=pt.y-cty, f9=pt.z-ctz;
        s0+=f0; s1+=f1; s2+=f2; s3+=f3; s4+=f4;
        s5+=f5; s6+=f6; s7+=f7; s8+=f8; s9+=f9;
#define QACC(idx,i,j) q_##i##_##j = fmaf(f##i, f##j, q_##i##_##j);
        PAIRS(QACC)
#undef QACC
        if (sub == 0) {
            const int cell = czi + cyi * NXC + cxi;
            atomicMax(&winner[cb * NCELLS + cell], p);
        }
    }

    // wave reduce all 65 scalars, wave leader stashes into LDS
    __shared__ float lds_part[4][65];
#define RED6(v) { v += __shfl_xor(v,32); v += __shfl_xor(v,16); v += __shfl_xor(v,8); \
                  v += __shfl_xor(v,4);  v += __shfl_xor(v,2);  v += __shfl_xor(v,1); }
    RED6(s0) RED6(s1) RED6(s2) RED6(s3) RED6(s4)
    RED6(s5) RED6(s6) RED6(s7) RED6(s8) RED6(s9)
#define QRED(idx,i,j) RED6(q_##i##_##j)
    PAIRS(QRED)
#undef QRED
#undef RED6
    if (lane == 0) {
        float* dst = &lds_part[wv][0];
        dst[0]=s0; dst[1]=s1; dst[2]=s2; dst[3]=s3; dst[4]=s4;
        dst[5]=s5; dst[6]=s6; dst[7]=s7; dst[8]=s8; dst[9]=s9;
#define QST(idx,i,j) dst[10+idx] = q_##i##_##j;
        PAIRS(QST)
#undef QST
    }
    __syncthreads();
    if (tid < 65) {   // per-block partial, NO global atomics
        const float acc = lds_part[0][tid] + lds_part[1][tid]
                        + lds_part[2][tid] + lds_part[3][tid];
        partial[tid * NBLK + blockIdx.x] = acc;
    }
}

// Pass 1b: reduce partials -> moments (LDS), fold through W -> scale/shift.
__global__ void k_finalize(const float* __restrict__ partial,
                           const float* __restrict__ W,
                           const float* __restrict__ gamma,
                           const float* __restrict__ beta,
                           float* __restrict__ ss) {
    __shared__ float mom[65];
    for (int i = threadIdx.x; i < 65; i += blockDim.x) {
        const float4* p4 = (const float4*)(partial + (size_t)i * NBLK);
        float a0=0.f, a1=0.f, a2=0.f, a3=0.f;
        for (int b = 0; b < NBLK/4; b++) {
            float4 v = p4[b];
            a0 += v.x; a1 += v.y; a2 += v.z; a3 += v.w;
        }
        mom[i] = (a0 + a1) + (a2 + a3);
    }
    __syncthreads();
    const int c = threadIdx.x;
    if (c >= 64) return;
    const double invN = 1.0 / ((double)NPILLARS * (double)MPTS);
    double wv[10];
#pragma unroll
    for (int i = 0; i < 10; i++) wv[i] = (double)W[i * NCHAN + c];
    double mu = 0.0;
#pragma unroll
    for (int i = 0; i < 10; i++) mu += (double)mom[i] * wv[i];
    mu *= invN;
    double e2 = 0.0;
#define QFOLD(idx,i,j) { double t = (double)mom[10+idx] * wv[i] * wv[j]; \
                         e2 += (i == j) ? t : 2.0 * t; }
    PAIRS(QFOLD)
#undef QFOLD
    e2 *= invN;
    const double var = e2 - mu * mu;
    const float scale = (float)((double)gamma[c] / sqrt(var + (double)BN_EPS));
    const float shift = beta[c] - (float)mu * scale;
    ss[c] = scale;
    ss[64 + c] = shift;
}

// Pass 2: per-pillar (32x10)@(10x64) via 2x v_mfma_f32_32x32x16_bf16,
// fused BN+relu+max over M, compact coalesced pv write.
// A-frag: row m = lane&31, k = (lane>>5)*8 + r  (no private arrays -> no scratch).
__global__ __launch_bounds__(256, 4)
void k_pv(const float4* __restrict__ pillars,
          const int* __restrict__ coords,
          const int* __restrict__ num_points,
          const float* __restrict__ W,
          const float* __restrict__ ss,
          float* __restrict__ pv) {
    const int tid  = threadIdx.x;
    const int lane = tid & 63;
    const int sub  = lane & 31;
    const int half = lane >> 5;
    const int wid    = (blockIdx.x * blockDim.x + tid) >> 6;
    const int nwaves = (gridDim.x * blockDim.x) >> 6;

    short8 bf0, bf1;
#pragma unroll
    for (int r = 0; r < 8; r++) {
        const int k = half * 8 + r;   // global loads w/ runtime guard: fine
        bf0[r] = (k < 10) ? f2bf(W[k * NCHAN + sub])      : (short)0;
        bf1[r] = (k < 10) ? f2bf(W[k * NCHAN + 32 + sub]) : (short)0;
    }
    const float scale0 = ss[sub],      shift0 = ss[64 + sub];
    const float scale1 = ss[32 + sub], shift1 = ss[96 + sub];

    for (int p = wid; p < NPILLARS; p += nwaves) {
        float4 pt = pillars[p * MPTS + sub];   // both halves: same m=sub (L1 hit)
        float sx = pt.x, sy = pt.y, sz = pt.z;
#pragma unroll
        for (int m = 16; m >= 1; m >>= 1) {
            sx += __shfl_xor(sx, m);
            sy += __shfl_xor(sy, m);
            sz += __shfl_xor(sz, m);
        }
        const float n = (float)num_points[p];
        const float mx = sx / n, my = sy / n, mz = sz / n;
        const float ctx = (float)coords[p*4+3] * PXc + XOFF;
        const float cty = (float)coords[p*4+2] * PYc + YOFF;
        const float ctz = (float)coords[p*4+1] * PZc + ZOFF;
        const short b0 = f2bf(pt.x),     b1 = f2bf(pt.y),     b2 = f2bf(pt.z),
                    b3 = f2bf(pt.w),     b4 = f2bf(pt.x-mx),  b5 = f2bf(pt.y-my),
                    b6 = f2bf(pt.z-mz),  b7 = f2bf(pt.x-ctx), b8 = f2bf(pt.y-cty),
                    b9 = f2bf(pt.z-ctz);
        short8 a;                               // per-element select: cndmask, no array
        a[0] = half ? b8 : b0;
        a[1] = half ? b9 : b1;
        a[2] = half ? (short)0 : b2;
        a[3] = half ? (short)0 : b3;
        a[4] = half ? (short)0 : b4;
        a[5] = half ? (short)0 : b5;
        a[6] = half ? (short)0 : b6;
        a[7] = half ? (short)0 : b7;
        float16 acc0 = {};
        float16 acc1 = {};
        acc0 = __builtin_amdgcn_mfma_f32_32x32x16_bf16(a, bf0, acc0, 0, 0, 0);
        acc1 = __builtin_amdgcn_mfma_f32_32x32x16_bf16(a, bf1, acc1, 0, 0, 0);
        // relu-then-max == max(0, max_m(scale*h+shift)); init 0 gives the relu floor.
        float m0 = 0.f, m1 = 0.f;
#pragma unroll
        for (int r = 0; r < 16; r++) {
            m0 = fmaxf(m0, fmaf(acc0[r], scale0, shift0));
            m1 = fmaxf(m1, fmaf(acc1[r], scale1, shift1));
        }
        m0 = fmaxf(m0, __shfl_xor(m0, 32));  // combine the two row-halves
        m1 = fmaxf(m1, __shfl_xor(m1, 32));
        pv[p * NCHAN + lane] = half ? m1 : m0;
    }
}

// Pass 3: output-ordered expand — every output element written coalesced once.
__global__ void k_expand(const int* __restrict__ winner,
                         const float* __restrict__ pv,
                         float* __restrict__ out) {
    const int idx = blockIdx.x * blockDim.x + threadIdx.x;  // group of 4 cells
    const int total4 = NB * NCELLS / 4;
    if (idx >= total4) return;
    const int b    = (idx << 2) / NCELLS;   // NCELLS % 4 == 0: no straddle
    const int cell = (idx << 2) - b * NCELLS;
    const int4 w = ((const int4*)winner)[idx];
    float* obase = out + (size_t)b * NCHAN * NCELLS + cell;
#pragma unroll 4
    for (int c = 0; c < NCHAN; c++) {
        float4 v;
        v.x = (w.x >= 0) ? pv[w.x * NCHAN + c] : 0.f;
        v.y = (w.y >= 0) ? pv[w.y * NCHAN + c] : 0.f;
        v.z = (w.z >= 0) ? pv[w.z * NCHAN + c] : 0.f;
        v.w = (w.w >= 0) ? pv[w.w * NCHAN + c] : 0.f;
        *reinterpret_cast<float4*>(obase + (size_t)c * NCELLS) = v;
    }
}

extern "C" void kernel_launch(void* const* d_in, const int* in_sizes, int n_in,
                              void* d_out, int out_size, void* d_ws, size_t ws_size,
                              hipStream_t stream) {
    const float4* pillars    = (const float4*)d_in[0];
    const int*    coords     = (const int*)d_in[1];
    const int*    num_points = (const int*)d_in[2];
    const float*  W          = (const float*)d_in[3];
    const float*  gamma      = (const float*)d_in[4];
    const float*  beta       = (const float*)d_in[5];
    float* out = (float*)d_out;

    char* ws = (char*)d_ws;
    float* ss     = (float*)ws;                       // 128 floats
    int*   winner = (int*)(ws + 4096);                // NB*NCELLS ints = 6.86 MB
    float* pv     = (float*)(ws + 4096 + (size_t)NB * NCELLS * sizeof(int)); // 24.6 MB
    float* partial = pv;  // alias: partial's live range ends before pv's begins

    hipMemsetAsync(winner, 0xFF, (size_t)NB * NCELLS * sizeof(int), stream);  // -1

    k_moments <<<NBLK, 256, 0, stream>>>(pillars, coords, num_points, partial, winner);
    k_finalize<<<1, 256, 0, stream>>>(partial, W, gamma, beta, ss);
    k_pv      <<<2048, 256, 0, stream>>>(pillars, coords, num_points, W, ss, pv);
    k_expand  <<<(NB * NCELLS / 4 + 255) / 256, 256, 0, stream>>>(winner, pv, out);
}